// Round 1
// 352.034 us; speedup vs baseline: 1.2788x; 1.2788x over previous
//
#include <hip/hip_runtime.h>
#include <cstdint>
#include <cstddef>

typedef unsigned short u16;
typedef unsigned int   u32;

#define LW     15
#define BNS    0.9999950000374997f   /* 1/sqrt(1+1e-5) */
#define SCALE  0.17677669529663687f  /* 1/sqrt(32) */

typedef __bf16 bf16x8 __attribute__((ext_vector_type(8)));
typedef float  f32x4  __attribute__((ext_vector_type(4)));

__device__ __forceinline__ u16 f2bf(float f){
  union { float f; u32 i; } v; v.f = f;
  u32 r = v.i + 0x7FFFu + ((v.i >> 16) & 1u);
  return (u16)(r >> 16);
}
__device__ __forceinline__ float bf2f(u16 u){
  union { u32 i; float f; } v; v.i = ((u32)u) << 16; return v.f;
}

// ---------------------------------------------------------------------------
// Kernel 0: convert qkv_w (196608) and proj_w (65536) fp32 -> bf16 in ws
// ---------------------------------------------------------------------------
__global__ void k_cvt_w(const float* __restrict__ qw, const float* __restrict__ pw,
                        u16* __restrict__ qwb, u16* __restrict__ pwb){
  const int i = blockIdx.x*256 + threadIdx.x;
  if (i < 196608) qwb[i] = f2bf(qw[i]);
  else            pwb[i - 196608] = f2bf(pw[i - 196608]);
}

// ---------------------------------------------------------------------------
// Kernel 1: CPB MLP -> tab[225][8] fp32
// ---------------------------------------------------------------------------
__global__ void k_cpb_mlp(const float* __restrict__ w1, const float* __restrict__ b1,
                          const float* __restrict__ w2, float* __restrict__ tab){
  const int e = blockIdx.x;        // 0..224
  const int c = threadIdx.x;       // 0..255
  const float a0 = (float)(e / LW - 7);
  const float a1 = (float)(e % LW - 7);
  const float cx = copysignf(log2f(fabsf(a0)*(8.f/7.f) + 1.f) * (1.f/3.f), a0);
  const float cy = copysignf(log2f(fabsf(a1)*(8.f/7.f) + 1.f) * (1.f/3.f), a1);
  float pre = (cx*w1[2*c] + cy*w1[2*c+1] + b1[c]) * BNS;
  float hid = pre / (1.f + __expf(-pre));   // silu
  __shared__ float hl[256];
  hl[c] = hid;
  __syncthreads();
  if (c < 8){
    float s = 0.f;
    for (int i = 0; i < 256; ++i) s += hl[i] * w2[c*256 + i];
    tab[e*8 + c] = s * BNS;
  }
}

// ---------------------------------------------------------------------------
// Kernel 2: biasT[h][key m][query n] = 16*sigmoid(tab[rpi(n,m)][h])
// ---------------------------------------------------------------------------
__global__ void k_bias_expand(const float* __restrict__ tab, float* __restrict__ biasT){
  const int id = blockIdx.x*256 + threadIdx.x;   // h*4096 + m*64 + n
  const int nq = id & 63;          // query token
  const int m  = (id >> 6) & 63;   // key token
  const int h  = id >> 12;
  const int dy = (nq >> 3) - (m >> 3) + 7;
  const int dx = (nq & 7)  - (m & 7)  + 7;
  const float v = tab[(dy*LW + dx)*8 + h];
  biasT[id] = 16.f / (1.f + __expf(-v));
}

// ---------------------------------------------------------------------------
// Kernel 3: fused qkv GEMM + MFMA windowed attention, HEAD-PAIR structured.
// Block = window, 256 thr = 4 waves.
// GEMM is row-partitioned: per head-pair iter (192 rows = q,k,v x 2 heads),
// wave w owns row-tiles {3w,3w+1,3w+2} and computes ALL 4 token tiles,
// reading B-fragments from the persistent xs LDS tile. Weight fragments are
// loaded by exactly ONE wave (4x less weight traffic than token-partitioned)
// and reused across 4 token tiles from registers.
// LDS 80384 B => 2 blocks/CU:
//   xs   u16[64][264]           @0      (33792, alive whole kernel)
//   q_b  u16[64][72] / P[2]     @33792  (18432; P_A overlays q_b - safe: each
//                                        wave reads only its own q rows first)
//   ks_  u16[64][72] / obuf[2]  @52224  (18432; obuf overlays ks_ after sync)
//   vsT  u16[64][72]            @70656  (9216; pair-local d rows 0..63)
//   linv f32[2][64]             @79872  (512)
// Barriers: 4 per pair-iter x 4 iters = 16 (was 32).
// ---------------------------------------------------------------------------
__global__ __launch_bounds__(256, 2) void k_qkv_attn(
    const float* __restrict__ x, const u16* __restrict__ qwb,
    const float* __restrict__ qb, const float* __restrict__ biasT,
    float* __restrict__ xout, u16* __restrict__ vout){
  const int win = blockIdx.x;
  const int b = win >> 6, wy = (win >> 3) & 7, wx = win & 7;
  __shared__ __align__(16) char smem[80384];
  u16*   xs   = (u16*)(smem);
  u16*   q_b  = (u16*)(smem + 33792);
  u16*   ks_  = (u16*)(smem + 52224);
  u16*   vsT  = (u16*)(smem + 70656);
  float* linv = (float*)(smem + 79872);

  const float* xbase = x + (size_t)b*256*4096 + (size_t)(wy*8)*64 + wx*8;
  for (int i = threadIdx.x; i < 16384; i += 256){
    const int c = i >> 6, n = i & 63;
    xs[n*264 + c] = f2bf(xbase[(size_t)c*4096 + ((n>>3)<<6) + (n&7)]);
  }
  const int wave = threadIdx.x >> 6, lane = threadIdx.x & 63;
  const int quad = lane >> 4, l16 = lane & 15;

  // epilogue indexing
  const int ed = threadIdx.x >> 3;           // 0..31 (d within head)
  const int eq = (threadIdx.x & 7) * 8;      // query group start
  const size_t epix = (size_t)(wy*8 + (threadIdx.x & 7))*64 + wx*8;

  const f32x4 zero4 = {0.f, 0.f, 0.f, 0.f};
  const int qn = wave*16 + l16;

  __syncthreads();   // xs ready

  for (int p = 0; p < 4; ++p){          // head pair: heads 2p, 2p+1
    // ---- qkv GEMM: 192 rows x 64 tokens, K=256; wave owns 3 row-tiles ----
    #pragma unroll
    for (int j = 0; j < 3; ++j){
      const int rt  = wave*3 + j;            // row-tile 0..11
      const int sec = rt >> 2;               // 0=q, 1=k, 2=v
      const int hs  = (rt >> 1) & 1;         // head within pair
      const int dl  = (rt & 1) * 16;         // dim-block base within head
      const int oga = sec*256 + (p*2 + hs)*32 + dl + l16;   // weight row (loads)
      bf16x8 af[8];
      #pragma unroll
      for (int kc = 0; kc < 8; ++kc)
        af[kc] = *(const bf16x8*)(qwb + (size_t)oga*256 + kc*32 + quad*8);
      const float4 bias4 = *(const float4*)&qb[sec*256 + (p*2 + hs)*32 + dl + quad*4];
      const int ddo = hs*32 + dl + quad*4;   // pair-local dim of acc rows
      #pragma unroll
      for (int tt = 0; tt < 4; ++tt){
        f32x4 acc = zero4;
        #pragma unroll
        for (int kc = 0; kc < 8; ++kc){
          bf16x8 bf = *(const bf16x8*)&xs[(tt*16 + l16)*264 + kc*32 + quad*8];
          acc = __builtin_amdgcn_mfma_f32_16x16x32_bf16(af[kc], bf, acc, 0, 0, 0);
        }
        const int tok = tt*16 + l16;
        if (sec < 2){
          ushort4 pk;
          pk.x = f2bf(acc[0] + bias4.x);
          pk.y = f2bf(acc[1] + bias4.y);
          pk.z = f2bf(acc[2] + bias4.z);
          pk.w = f2bf(acc[3] + bias4.w);
          u16* dst = (sec == 0) ? q_b : ks_;
          *(ushort4*)&dst[tok*72 + ddo] = pk;
        } else {
          #pragma unroll
          for (int r = 0; r < 4; ++r)
            vsT[(ddo + r)*72 + tok] = f2bf(acc[r] + ((const float*)&bias4)[r]);
        }
      }
    }
    __syncthreads();

    // ---- QK^T + softmax + P, both heads (qf for both loaded BEFORE P_A
    //      overwrites q_b; each wave touches only its own query rows) ----
    bf16x8 qf2[2];
    qf2[0] = *(const bf16x8*)&q_b[qn*72 +  0 + quad*8];
    qf2[1] = *(const bf16x8*)&q_b[qn*72 + 32 + quad*8];
    #pragma unroll
    for (int h2 = 0; h2 < 2; ++h2){
      const int h = p*2 + h2;
      f32x4 st[4];
      #pragma unroll
      for (int kt = 0; kt < 4; ++kt){
        bf16x8 ka = *(const bf16x8*)&ks_[(kt*16 + l16)*72 + h2*32 + quad*8];
        st[kt] = __builtin_amdgcn_mfma_f32_16x16x32_bf16(ka, qf2[h2], zero4, 0, 0, 0);
      }
      float sc[16], mx = -1e30f;
      #pragma unroll
      for (int kt = 0; kt < 4; ++kt)
        #pragma unroll
        for (int r = 0; r < 4; ++r){
          const int key = kt*16 + quad*4 + r;
          const float v = st[kt][r]*SCALE + biasT[(h<<12) + (key<<6) + qn];
          sc[kt*4+r] = v; mx = fmaxf(mx, v);
        }
      mx = fmaxf(mx, __shfl_xor(mx, 16));
      mx = fmaxf(mx, __shfl_xor(mx, 32));
      float sum = 0.f;
      #pragma unroll
      for (int i = 0; i < 16; ++i){ sc[i] = __expf(sc[i] - mx); sum += sc[i]; }
      sum += __shfl_xor(sum, 16);
      sum += __shfl_xor(sum, 32);
      if (quad == 0) linv[h2*64 + qn] = 1.f / sum;
      u16* P = (u16*)(smem + 33792 + h2*9216);
      #pragma unroll
      for (int kt = 0; kt < 4; ++kt){
        ushort4 pk;
        pk.x = f2bf(sc[kt*4+0]); pk.y = f2bf(sc[kt*4+1]);
        pk.z = f2bf(sc[kt*4+2]); pk.w = f2bf(sc[kt*4+3]);
        *(ushort4*)&P[qn*72 + kt*16 + quad*4] = pk;
      }
    }
    __syncthreads();   // all ks_ reads done before obuf overlays it

    // ---- PV: O[query][d], both heads ----
    #pragma unroll
    for (int h2 = 0; h2 < 2; ++h2){
      const u16* P = (const u16*)(smem + 33792 + h2*9216);
      float* obuf  = (float*)(smem + 52224 + h2*9216);
      bf16x8 pa0 = *(const bf16x8*)&P[qn*72 +  0 + quad*8];
      bf16x8 pa1 = *(const bf16x8*)&P[qn*72 + 32 + quad*8];
      #pragma unroll
      for (int dt = 0; dt < 2; ++dt){
        bf16x8 bv0 = *(const bf16x8*)&vsT[(h2*32 + dt*16 + l16)*72 +  0 + quad*8];
        bf16x8 bv1 = *(const bf16x8*)&vsT[(h2*32 + dt*16 + l16)*72 + 32 + quad*8];
        f32x4 o = __builtin_amdgcn_mfma_f32_16x16x32_bf16(pa0, bv0, zero4, 0, 0, 0);
        o = __builtin_amdgcn_mfma_f32_16x16x32_bf16(pa1, bv1, o, 0, 0, 0);
        #pragma unroll
        for (int r = 0; r < 4; ++r){
          const float ls = linv[h2*64 + wave*16 + quad*4 + r];
          obuf[(dt*16 + l16)*72 + wave*16 + quad*4 + r] = o[r]*ls;
        }
      }
    }
    __syncthreads();

    // ---- epilogue: coalesced O (fp32) + V (bf16) stores, both heads ----
    #pragma unroll
    for (int h2 = 0; h2 < 2; ++h2){
      const float* obuf = (const float*)(smem + 52224 + h2*9216);
      const size_t gp = ((size_t)(b*256 + (p*2 + h2)*32 + ed))*4096 + epix;
      float4 o0 = *(const float4*)&obuf[ed*72 + eq];
      float4 o1 = *(const float4*)&obuf[ed*72 + eq + 4];
      *(float4*)&xout[gp]     = o0;
      *(float4*)&xout[gp + 4] = o1;
      ushort4 v0 = *(const ushort4*)&vsT[(h2*32 + ed)*72 + eq];
      ushort4 v1 = *(const ushort4*)&vsT[(h2*32 + ed)*72 + eq + 4];
      *(ushort4*)&vout[gp]     = v0;
      *(ushort4*)&vout[gp + 4] = v1;
    }
    __syncthreads();   // protect LDS before next pair's GEMM overwrites
  }
}

// ---------------------------------------------------------------------------
// Kernel 4: depthwise 7x7 + residual, IN PLACE on io (fp32).
// Register-blocked: thread computes 4x4 outputs; 30 b128 LDS reads vs 784.
// ---------------------------------------------------------------------------
__global__ __launch_bounds__(256) void k_dwconv(
    const u16* __restrict__ vimg, const float* __restrict__ dww,
    float* __restrict__ io){
  const int b = blockIdx.x >> 8, c = blockIdx.x & 255;
  __shared__ float tile[70*72];   // zero-padded halo
  const size_t base = ((size_t)(b*256 + c)) * 4096;
  for (int i = threadIdx.x; i < 70*72; i += 256) tile[i] = 0.f;
  float w[49];
  #pragma unroll
  for (int j = 0; j < 49; ++j) w[j] = dww[c*49 + j];
  __syncthreads();
  for (int i = threadIdx.x; i < 4096; i += 256){
    const int y = i >> 6, xx = i & 63;
    tile[(y+3)*72 + (xx+3)] = bf2f(vimg[base + i]);
  }
  __syncthreads();

  const int x0 = (threadIdx.x & 15) * 4;
  const int y0 = (threadIdx.x >> 4) * 4;
  float acc[4][4];
  #pragma unroll
  for (int i = 0; i < 4; ++i)
    #pragma unroll
    for (int j = 0; j < 4; ++j) acc[i][j] = 0.f;

  #pragma unroll
  for (int ty = 0; ty < 10; ++ty){
    const float* rp = &tile[(y0 + ty)*72 + x0];
    float r[12];
    *(float4*)&r[0] = *(const float4*)&rp[0];
    *(float4*)&r[4] = *(const float4*)&rp[4];
    *(float4*)&r[8] = *(const float4*)&rp[8];
    #pragma unroll
    for (int oy = 0; oy < 4; ++oy){
      if (ty >= oy && ty - oy <= 6){
        const int ky = ty - oy;
        #pragma unroll
        for (int ox = 0; ox < 4; ++ox)
          #pragma unroll
          for (int kx = 0; kx < 7; ++kx)
            acc[oy][ox] += w[ky*7 + kx] * r[ox + kx];
      }
    }
  }
  #pragma unroll
  for (int oy = 0; oy < 4; ++oy){
    const size_t gi = base + (size_t)(y0 + oy)*64 + x0;
    float4 res = *(const float4*)&io[gi];
    res.x += acc[oy][0]; res.y += acc[oy][1];
    res.z += acc[oy][2]; res.w += acc[oy][3];
    *(float4*)&io[gi] = res;
  }
}

// ---------------------------------------------------------------------------
// Kernel 5: proj GEMM per image row (MFMA), IN PLACE on io fp32.
// ---------------------------------------------------------------------------
__global__ void k_proj(const u16* __restrict__ pwb, const float* __restrict__ pb,
                       float* __restrict__ io){
  const int row = blockIdx.x;           // b*64 + y
  const int b = row >> 6, y = row & 63;
  __shared__ __align__(16) u16 ts[64*264];   // [pixel n][c] bf16, pad +8
  const float* tbase = io + (size_t)b*256*4096 + (size_t)y*64;
  for (int i = threadIdx.x; i < 16384; i += 256){
    const int c = i >> 6, n = i & 63;
    ts[n*264 + c] = f2bf(tbase[(size_t)c*4096 + n]);
  }
  __syncthreads();
  const int wave = threadIdx.x >> 6, lane = threadIdx.x & 63;
  const int quad = lane >> 4, l16 = lane & 15;
  for (int oi = 0; oi < 4; ++oi){
    const int ot = wave*4 + oi;          // 16 o-tiles of 16
    const int orow = ot*16 + l16;
    bf16x8 af[8];
    #pragma unroll
    for (int kc = 0; kc < 8; ++kc)
      af[kc] = *reinterpret_cast<const bf16x8*>(pwb + (size_t)orow*256 + kc*32 + quad*8);
    #pragma unroll
    for (int nt = 0; nt < 4; ++nt){
      f32x4 acc = {0.f, 0.f, 0.f, 0.f};
      #pragma unroll
      for (int kc = 0; kc < 8; ++kc){
        bf16x8 bf = *reinterpret_cast<const bf16x8*>(&ts[(nt*16 + l16)*264 + kc*32 + quad*8]);
        acc = __builtin_amdgcn_mfma_f32_16x16x32_bf16(af[kc], bf, acc, 0, 0, 0);
      }
      #pragma unroll
      for (int r = 0; r < 4; ++r){
        const int o = ot*16 + quad*4 + r;
        io[((size_t)(b*256 + o))*4096 + (size_t)y*64 + nt*16 + l16] = acc[r] + pb[o];
      }
    }
  }
}

// ---------------------------------------------------------------------------
extern "C" void kernel_launch(void* const* d_in, const int* in_sizes, int n_in,
                              void* d_out, int out_size, void* d_ws, size_t ws_size,
                              hipStream_t stream){
  const float* x   = (const float*)d_in[0];
  const float* qw  = (const float*)d_in[1];
  const float* qb  = (const float*)d_in[2];
  const float* pw  = (const float*)d_in[3];
  const float* pb  = (const float*)d_in[4];
  const float* w1  = (const float*)d_in[5];
  const float* b1  = (const float*)d_in[6];
  const float* w2  = (const float*)d_in[7];
  const float* dww = (const float*)d_in[8];

  // ws: tab 8KB | biasT 128KB | qwb 384KB | pwb 128KB | vimg 32MB (~34.2 MB)
  char* ws = (char*)d_ws;
  float* tab   = (float*)(ws);
  float* biasT = (float*)(ws + 8192);
  u16*   qwb   = (u16*)  (ws + 139264);
  u16*   pwb   = (u16*)  (ws + 532480);
  u16*   vimg  = (u16*)  (ws + 663552);
  float* out   = (float*)d_out;          // doubles as attn-out intermediate

  k_cvt_w      <<<1024, 256, 0, stream>>>(qw, pw, qwb, pwb);
  k_cpb_mlp    <<<225,  256, 0, stream>>>(w1, b1, w2, tab);
  k_bias_expand<<<128,  256, 0, stream>>>(tab, biasT);
  k_qkv_attn   <<<1024, 256, 0, stream>>>(x, qwb, qb, biasT, out, vimg);
  k_dwconv     <<<4096, 256, 0, stream>>>(vimg, dww, out);
  k_proj       <<<1024, 256, 0, stream>>>(pwb, pb, out);
}

// Round 2
// 321.258 us; speedup vs baseline: 1.4013x; 1.0958x over previous
//
#include <hip/hip_runtime.h>
#include <cstdint>
#include <cstddef>

typedef unsigned short u16;
typedef unsigned int   u32;

#define LW     15
#define BNS    0.9999950000374997f   /* 1/sqrt(1+1e-5) */
#define SCALE  0.17677669529663687f  /* 1/sqrt(32) */

typedef __bf16 bf16x8 __attribute__((ext_vector_type(8)));
typedef float  f32x4  __attribute__((ext_vector_type(4)));
typedef u16    u16x8  __attribute__((ext_vector_type(8)));

__device__ __forceinline__ u16 f2bf(float f){
  union { float f; u32 i; } v; v.f = f;
  u32 r = v.i + 0x7FFFu + ((v.i >> 16) & 1u);
  return (u16)(r >> 16);
}
__device__ __forceinline__ float bf2f(u16 u){
  union { u32 i; float f; } v; v.i = ((u32)u) << 16; return v.f;
}

// ---------------------------------------------------------------------------
// Kernel 0: convert qkv_w (196608) and proj_w (65536) fp32 -> bf16 in ws
// ---------------------------------------------------------------------------
__global__ void k_cvt_w(const float* __restrict__ qw, const float* __restrict__ pw,
                        u16* __restrict__ qwb, u16* __restrict__ pwb){
  const int i = blockIdx.x*256 + threadIdx.x;
  if (i < 196608) qwb[i] = f2bf(qw[i]);
  else            pwb[i - 196608] = f2bf(pw[i - 196608]);
}

// ---------------------------------------------------------------------------
// Kernel 1: CPB MLP -> tab[225][8] fp32
// ---------------------------------------------------------------------------
__global__ void k_cpb_mlp(const float* __restrict__ w1, const float* __restrict__ b1,
                          const float* __restrict__ w2, float* __restrict__ tab){
  const int e = blockIdx.x;        // 0..224
  const int c = threadIdx.x;       // 0..255
  const float a0 = (float)(e / LW - 7);
  const float a1 = (float)(e % LW - 7);
  const float cx = copysignf(log2f(fabsf(a0)*(8.f/7.f) + 1.f) * (1.f/3.f), a0);
  const float cy = copysignf(log2f(fabsf(a1)*(8.f/7.f) + 1.f) * (1.f/3.f), a1);
  float pre = (cx*w1[2*c] + cy*w1[2*c+1] + b1[c]) * BNS;
  float hid = pre / (1.f + __expf(-pre));   // silu
  __shared__ float hl[256];
  hl[c] = hid;
  __syncthreads();
  if (c < 8){
    float s = 0.f;
    for (int i = 0; i < 256; ++i) s += hl[i] * w2[c*256 + i];
    tab[e*8 + c] = s * BNS;
  }
}

// ---------------------------------------------------------------------------
// Kernel 2: biasT[h][key m][query n] = 16*sigmoid(tab[rpi(n,m)][h])
// ---------------------------------------------------------------------------
__global__ void k_bias_expand(const float* __restrict__ tab, float* __restrict__ biasT){
  const int id = blockIdx.x*256 + threadIdx.x;   // h*4096 + m*64 + n
  const int nq = id & 63;          // query token
  const int m  = (id >> 6) & 63;   // key token
  const int h  = id >> 12;
  const int dy = (nq >> 3) - (m >> 3) + 7;
  const int dx = (nq & 7)  - (m & 7)  + 7;
  const float v = tab[(dy*LW + dx)*8 + h];
  biasT[id] = 16.f / (1.f + __expf(-v));
}

// ---------------------------------------------------------------------------
// Kernel 3: fused qkv GEMM + MFMA windowed attention, HEAD-PAIR structured.
// Block = window, 256 thr = 4 waves.
// GEMM: row-partitioned (wave owns 3 row-tiles of the 192-row head-pair
// slice). ILP restructure: af[3][8] preloaded per pair; kc-outer loop with
// 6 INDEPENDENT accumulator chains (3 row-tiles x 2 token-tiles, two token
// halves) -> MFMA latency hidden within a wave. xs B-fragments read once per
// (kc, token-tile) instead of once per (j, kc, token-tile): 3x fewer LDS
// reads than round 1.
// Staging: float4 global loads (16 per thread vs 64 scalar).
// LDS 80384 B => 2 blocks/CU (unchanged layout):
//   xs   u16[64][264]           @0      (33792, alive whole kernel)
//   q_b  u16[64][72] / P[2]     @33792  (18432)
//   ks_  u16[64][72] / obuf[2]  @52224  (18432)
//   vsT  u16[64][72]            @70656  (9216)
//   linv f32[2][64]             @79872  (512)
// ---------------------------------------------------------------------------
__global__ __launch_bounds__(256, 2) void k_qkv_attn(
    const float* __restrict__ x, const u16* __restrict__ qwb,
    const float* __restrict__ qb, const float* __restrict__ biasT,
    float* __restrict__ xout, u16* __restrict__ vout){
  const int win = blockIdx.x;
  const int b = win >> 6, wy = (win >> 3) & 7, wx = win & 7;
  __shared__ __align__(16) char smem[80384];
  u16*   xs   = (u16*)(smem);
  u16*   q_b  = (u16*)(smem + 33792);
  u16*   ks_  = (u16*)(smem + 52224);
  u16*   vsT  = (u16*)(smem + 70656);
  float* linv = (float*)(smem + 79872);

  const float* xbase = x + (size_t)b*256*4096 + (size_t)(wy*8)*64 + wx*8;
  // float4 staging: thread i covers channel c = i>>4, 4 consecutive tokens
  for (int i = threadIdx.x; i < 4096; i += 256){
    const int c  = i >> 4;
    const int g  = i & 15;               // py = g>>1, half-row = g&1
    const int py = g >> 1, xh = (g & 1) * 4;
    float4 v4 = *(const float4*)&xbase[(size_t)c*4096 + py*64 + xh];
    const int n0 = py*8 + xh;
    xs[(n0+0)*264 + c] = f2bf(v4.x);
    xs[(n0+1)*264 + c] = f2bf(v4.y);
    xs[(n0+2)*264 + c] = f2bf(v4.z);
    xs[(n0+3)*264 + c] = f2bf(v4.w);
  }
  const int wave = threadIdx.x >> 6, lane = threadIdx.x & 63;
  const int quad = lane >> 4, l16 = lane & 15;

  // epilogue indexing
  const int ed = threadIdx.x >> 3;           // 0..31 (d within head)
  const int eq = (threadIdx.x & 7) * 8;      // query group start
  const size_t epix = (size_t)(wy*8 + (threadIdx.x & 7))*64 + wx*8;

  const f32x4 zero4 = {0.f, 0.f, 0.f, 0.f};
  const int qn = wave*16 + l16;

  __syncthreads();   // xs ready

  for (int p = 0; p < 4; ++p){          // head pair: heads 2p, 2p+1
    // ---- qkv GEMM: 192 rows x 64 tokens, K=256; wave owns 3 row-tiles ----
    bf16x8 af[3][8];
    float4 bias4[3];
    #pragma unroll
    for (int j = 0; j < 3; ++j){
      const int rt  = wave*3 + j;            // row-tile 0..11
      const int sec = rt >> 2;               // 0=q, 1=k, 2=v
      const int hs  = (rt >> 1) & 1;         // head within pair
      const int dl  = (rt & 1) * 16;         // dim-block base within head
      const int oga = sec*256 + (p*2 + hs)*32 + dl + l16;   // weight row
      #pragma unroll
      for (int kc = 0; kc < 8; ++kc)
        af[j][kc] = *(const bf16x8*)(qwb + (size_t)oga*256 + kc*32 + quad*8);
      bias4[j] = *(const float4*)&qb[sec*256 + (p*2 + hs)*32 + dl + quad*4];
    }
    #pragma unroll
    for (int th = 0; th < 2; ++th){          // token-tile halves
      f32x4 acc[3][2];
      #pragma unroll
      for (int j = 0; j < 3; ++j){ acc[j][0] = zero4; acc[j][1] = zero4; }
      #pragma unroll
      for (int kc = 0; kc < 8; ++kc){
        bf16x8 b0 = *(const bf16x8*)&xs[((th*2+0)*16 + l16)*264 + kc*32 + quad*8];
        bf16x8 b1 = *(const bf16x8*)&xs[((th*2+1)*16 + l16)*264 + kc*32 + quad*8];
        #pragma unroll
        for (int j = 0; j < 3; ++j){
          acc[j][0] = __builtin_amdgcn_mfma_f32_16x16x32_bf16(af[j][kc], b0, acc[j][0], 0, 0, 0);
          acc[j][1] = __builtin_amdgcn_mfma_f32_16x16x32_bf16(af[j][kc], b1, acc[j][1], 0, 0, 0);
        }
      }
      #pragma unroll
      for (int j = 0; j < 3; ++j){
        const int rt  = wave*3 + j;
        const int sec = rt >> 2;
        const int hs  = (rt >> 1) & 1;
        const int dl  = (rt & 1) * 16;
        const int ddo = hs*32 + dl + quad*4;
        #pragma unroll
        for (int t2 = 0; t2 < 2; ++t2){
          const int tok = (th*2 + t2)*16 + l16;
          const f32x4 a = acc[j][t2];
          if (sec < 2){
            ushort4 pk;
            pk.x = f2bf(a[0] + bias4[j].x);
            pk.y = f2bf(a[1] + bias4[j].y);
            pk.z = f2bf(a[2] + bias4[j].z);
            pk.w = f2bf(a[3] + bias4[j].w);
            u16* dst = (sec == 0) ? q_b : ks_;
            *(ushort4*)&dst[tok*72 + ddo] = pk;
          } else {
            vsT[(ddo+0)*72 + tok] = f2bf(a[0] + bias4[j].x);
            vsT[(ddo+1)*72 + tok] = f2bf(a[1] + bias4[j].y);
            vsT[(ddo+2)*72 + tok] = f2bf(a[2] + bias4[j].z);
            vsT[(ddo+3)*72 + tok] = f2bf(a[3] + bias4[j].w);
          }
        }
      }
    }
    __syncthreads();

    // ---- QK^T + softmax + P, both heads (qf for both loaded BEFORE P_A
    //      overwrites q_b; each wave touches only its own query rows) ----
    bf16x8 qf2[2];
    qf2[0] = *(const bf16x8*)&q_b[qn*72 +  0 + quad*8];
    qf2[1] = *(const bf16x8*)&q_b[qn*72 + 32 + quad*8];
    #pragma unroll
    for (int h2 = 0; h2 < 2; ++h2){
      const int h = p*2 + h2;
      f32x4 st[4];
      #pragma unroll
      for (int kt = 0; kt < 4; ++kt){
        bf16x8 ka = *(const bf16x8*)&ks_[(kt*16 + l16)*72 + h2*32 + quad*8];
        st[kt] = __builtin_amdgcn_mfma_f32_16x16x32_bf16(ka, qf2[h2], zero4, 0, 0, 0);
      }
      float sc[16], mx = -1e30f;
      #pragma unroll
      for (int kt = 0; kt < 4; ++kt)
        #pragma unroll
        for (int r = 0; r < 4; ++r){
          const int key = kt*16 + quad*4 + r;
          const float v = st[kt][r]*SCALE + biasT[(h<<12) + (key<<6) + qn];
          sc[kt*4+r] = v; mx = fmaxf(mx, v);
        }
      mx = fmaxf(mx, __shfl_xor(mx, 16));
      mx = fmaxf(mx, __shfl_xor(mx, 32));
      float sum = 0.f;
      #pragma unroll
      for (int i = 0; i < 16; ++i){ sc[i] = __expf(sc[i] - mx); sum += sc[i]; }
      sum += __shfl_xor(sum, 16);
      sum += __shfl_xor(sum, 32);
      if (quad == 0) linv[h2*64 + qn] = 1.f / sum;
      u16* P = (u16*)(smem + 33792 + h2*9216);
      #pragma unroll
      for (int kt = 0; kt < 4; ++kt){
        ushort4 pk;
        pk.x = f2bf(sc[kt*4+0]); pk.y = f2bf(sc[kt*4+1]);
        pk.z = f2bf(sc[kt*4+2]); pk.w = f2bf(sc[kt*4+3]);
        *(ushort4*)&P[qn*72 + kt*16 + quad*4] = pk;
      }
    }
    __syncthreads();   // all ks_ reads done before obuf overlays it

    // ---- PV: O[query][d], both heads ----
    #pragma unroll
    for (int h2 = 0; h2 < 2; ++h2){
      const u16* P = (const u16*)(smem + 33792 + h2*9216);
      float* obuf  = (float*)(smem + 52224 + h2*9216);
      bf16x8 pa0 = *(const bf16x8*)&P[qn*72 +  0 + quad*8];
      bf16x8 pa1 = *(const bf16x8*)&P[qn*72 + 32 + quad*8];
      #pragma unroll
      for (int dt = 0; dt < 2; ++dt){
        bf16x8 bv0 = *(const bf16x8*)&vsT[(h2*32 + dt*16 + l16)*72 +  0 + quad*8];
        bf16x8 bv1 = *(const bf16x8*)&vsT[(h2*32 + dt*16 + l16)*72 + 32 + quad*8];
        f32x4 o = __builtin_amdgcn_mfma_f32_16x16x32_bf16(pa0, bv0, zero4, 0, 0, 0);
        o = __builtin_amdgcn_mfma_f32_16x16x32_bf16(pa1, bv1, o, 0, 0, 0);
        #pragma unroll
        for (int r = 0; r < 4; ++r){
          const float ls = linv[h2*64 + wave*16 + quad*4 + r];
          obuf[(dt*16 + l16)*72 + wave*16 + quad*4 + r] = o[r]*ls;
        }
      }
    }
    __syncthreads();

    // ---- epilogue: coalesced O (fp32) + V (bf16) stores, both heads ----
    #pragma unroll
    for (int h2 = 0; h2 < 2; ++h2){
      const float* obuf = (const float*)(smem + 52224 + h2*9216);
      const size_t gp = ((size_t)(b*256 + (p*2 + h2)*32 + ed))*4096 + epix;
      float4 o0 = *(const float4*)&obuf[ed*72 + eq];
      float4 o1 = *(const float4*)&obuf[ed*72 + eq + 4];
      *(float4*)&xout[gp]     = o0;
      *(float4*)&xout[gp + 4] = o1;
      u16x8 v8 = *(const u16x8*)&vsT[(h2*32 + ed)*72 + eq];
      *(u16x8*)&vout[gp] = v8;
    }
    __syncthreads();   // protect LDS before next pair's GEMM overwrites
  }
}

// ---------------------------------------------------------------------------
// Kernel 4: depthwise 7x7 + residual, IN PLACE on io (fp32).
// Register-blocked 4x4 outputs; staging vectorized (u16x8 loads).
// ---------------------------------------------------------------------------
__global__ __launch_bounds__(256) void k_dwconv(
    const u16* __restrict__ vimg, const float* __restrict__ dww,
    float* __restrict__ io){
  const int b = blockIdx.x >> 8, c = blockIdx.x & 255;
  __shared__ float tile[70*72];   // zero-padded halo
  const size_t base = ((size_t)(b*256 + c)) * 4096;
  for (int i = threadIdx.x; i < 1260; i += 256)
    *(float4*)&tile[i*4] = (float4){0.f, 0.f, 0.f, 0.f};
  float w[49];
  #pragma unroll
  for (int j = 0; j < 49; ++j) w[j] = dww[c*49 + j];
  __syncthreads();
  for (int i = threadIdx.x; i < 512; i += 256){
    const int y = i >> 3, x8 = (i & 7) * 8;
    u16x8 v = *(const u16x8*)&vimg[base + y*64 + x8];
    #pragma unroll
    for (int j = 0; j < 8; ++j) tile[(y+3)*72 + x8 + 3 + j] = bf2f(v[j]);
  }
  __syncthreads();

  const int x0 = (threadIdx.x & 15) * 4;
  const int y0 = (threadIdx.x >> 4) * 4;
  float acc[4][4];
  #pragma unroll
  for (int i = 0; i < 4; ++i)
    #pragma unroll
    for (int j = 0; j < 4; ++j) acc[i][j] = 0.f;

  #pragma unroll
  for (int ty = 0; ty < 10; ++ty){
    const float* rp = &tile[(y0 + ty)*72 + x0];
    float r[12];
    *(float4*)&r[0] = *(const float4*)&rp[0];
    *(float4*)&r[4] = *(const float4*)&rp[4];
    *(float4*)&r[8] = *(const float4*)&rp[8];
    #pragma unroll
    for (int oy = 0; oy < 4; ++oy){
      if (ty >= oy && ty - oy <= 6){
        const int ky = ty - oy;
        #pragma unroll
        for (int ox = 0; ox < 4; ++ox)
          #pragma unroll
          for (int kx = 0; kx < 7; ++kx)
            acc[oy][ox] += w[ky*7 + kx] * r[ox + kx];
      }
    }
  }
  #pragma unroll
  for (int oy = 0; oy < 4; ++oy){
    const size_t gi = base + (size_t)(y0 + oy)*64 + x0;
    float4 res = *(const float4*)&io[gi];
    res.x += acc[oy][0]; res.y += acc[oy][1];
    res.z += acc[oy][2]; res.w += acc[oy][3];
    *(float4*)&io[gi] = res;
  }
}

// ---------------------------------------------------------------------------
// Kernel 5: proj GEMM per image row (MFMA), IN PLACE on io fp32.
// ILP restructure: o-tile pairs with af held in regs, kc-outer, 8 independent
// accumulator chains; float4 staging loads.
// ---------------------------------------------------------------------------
__global__ __launch_bounds__(256) void k_proj(
    const u16* __restrict__ pwb, const float* __restrict__ pb,
    float* __restrict__ io){
  const int row = blockIdx.x;           // b*64 + y
  const int b = row >> 6, y = row & 63;
  __shared__ __align__(16) u16 ts[64*264];   // [pixel n][c] bf16, pad +8
  const float* tbase = io + (size_t)b*256*4096 + (size_t)y*64;
  for (int i = threadIdx.x; i < 4096; i += 256){
    const int c = i >> 4, n0 = (i & 15) * 4;
    float4 v4 = *(const float4*)&tbase[(size_t)c*4096 + n0];
    ts[(n0+0)*264 + c] = f2bf(v4.x);
    ts[(n0+1)*264 + c] = f2bf(v4.y);
    ts[(n0+2)*264 + c] = f2bf(v4.z);
    ts[(n0+3)*264 + c] = f2bf(v4.w);
  }
  __syncthreads();
  const int wave = threadIdx.x >> 6, lane = threadIdx.x & 63;
  const int quad = lane >> 4, l16 = lane & 15;
  const f32x4 zero4 = {0.f, 0.f, 0.f, 0.f};
  #pragma unroll
  for (int op = 0; op < 2; ++op){        // o-tile pairs
    bf16x8 af2[2][8];
    #pragma unroll
    for (int oj = 0; oj < 2; ++oj){
      const int orow = (wave*4 + op*2 + oj)*16 + l16;
      #pragma unroll
      for (int kc = 0; kc < 8; ++kc)
        af2[oj][kc] = *(const bf16x8*)(pwb + (size_t)orow*256 + kc*32 + quad*8);
    }
    f32x4 acc[2][4];
    #pragma unroll
    for (int oj = 0; oj < 2; ++oj)
      #pragma unroll
      for (int nt = 0; nt < 4; ++nt) acc[oj][nt] = zero4;
    #pragma unroll
    for (int kc = 0; kc < 8; ++kc){
      bf16x8 bf[4];
      #pragma unroll
      for (int nt = 0; nt < 4; ++nt)
        bf[nt] = *(const bf16x8*)&ts[(nt*16 + l16)*264 + kc*32 + quad*8];
      #pragma unroll
      for (int oj = 0; oj < 2; ++oj)
        #pragma unroll
        for (int nt = 0; nt < 4; ++nt)
          acc[oj][nt] = __builtin_amdgcn_mfma_f32_16x16x32_bf16(af2[oj][kc], bf[nt], acc[oj][nt], 0, 0, 0);
    }
    #pragma unroll
    for (int oj = 0; oj < 2; ++oj){
      const int ot = wave*4 + op*2 + oj;
      #pragma unroll
      for (int nt = 0; nt < 4; ++nt)
        #pragma unroll
        for (int r = 0; r < 4; ++r){
          const int o = ot*16 + quad*4 + r;
          io[((size_t)(b*256 + o))*4096 + (size_t)y*64 + nt*16 + l16] = acc[oj][nt][r] + pb[o];
        }
    }
  }
}

// ---------------------------------------------------------------------------
extern "C" void kernel_launch(void* const* d_in, const int* in_sizes, int n_in,
                              void* d_out, int out_size, void* d_ws, size_t ws_size,
                              hipStream_t stream){
  const float* x   = (const float*)d_in[0];
  const float* qw  = (const float*)d_in[1];
  const float* qb  = (const float*)d_in[2];
  const float* pw  = (const float*)d_in[3];
  const float* pb  = (const float*)d_in[4];
  const float* w1  = (const float*)d_in[5];
  const float* b1  = (const float*)d_in[6];
  const float* w2  = (const float*)d_in[7];
  const float* dww = (const float*)d_in[8];

  // ws: tab 8KB | biasT 128KB | qwb 384KB | pwb 128KB | vimg 32MB (~34.2 MB)
  char* ws = (char*)d_ws;
  float* tab   = (float*)(ws);
  float* biasT = (float*)(ws + 8192);
  u16*   qwb   = (u16*)  (ws + 139264);
  u16*   pwb   = (u16*)  (ws + 532480);
  u16*   vimg  = (u16*)  (ws + 663552);
  float* out   = (float*)d_out;          // doubles as attn-out intermediate

  k_cvt_w      <<<1024, 256, 0, stream>>>(qw, pw, qwb, pwb);
  k_cpb_mlp    <<<225,  256, 0, stream>>>(w1, b1, w2, tab);
  k_bias_expand<<<128,  256, 0, stream>>>(tab, biasT);
  k_qkv_attn   <<<1024, 256, 0, stream>>>(x, qwb, qb, biasT, out, vimg);
  k_dwconv     <<<4096, 256, 0, stream>>>(vimg, dww, out);
  k_proj       <<<1024, 256, 0, stream>>>(pwb, pb, out);
}

// Round 3
// 307.245 us; speedup vs baseline: 1.4652x; 1.0456x over previous
//
#include <hip/hip_runtime.h>
#include <cstdint>
#include <cstddef>

typedef unsigned short u16;
typedef unsigned int   u32;

#define LW     15
#define BNS    0.9999950000374997f   /* 1/sqrt(1+1e-5) */
#define SCALE  0.17677669529663687f  /* 1/sqrt(32) */

typedef __bf16 bf16x8 __attribute__((ext_vector_type(8)));
typedef float  f32x4  __attribute__((ext_vector_type(4)));
typedef u16    u16x8  __attribute__((ext_vector_type(8)));

__device__ __forceinline__ u16 f2bf(float f){
  union { float f; u32 i; } v; v.f = f;
  u32 r = v.i + 0x7FFFu + ((v.i >> 16) & 1u);
  return (u16)(r >> 16);
}
__device__ __forceinline__ float bf2f(u16 u){
  union { u32 i; float f; } v; v.i = ((u32)u) << 16; return v.f;
}

// ---------------------------------------------------------------------------
// Kernel 0: convert qkv_w (196608) and proj_w (65536) fp32 -> bf16 in ws
// ---------------------------------------------------------------------------
__global__ void k_cvt_w(const float* __restrict__ qw, const float* __restrict__ pw,
                        u16* __restrict__ qwb, u16* __restrict__ pwb){
  const int i = blockIdx.x*256 + threadIdx.x;
  if (i < 196608) qwb[i] = f2bf(qw[i]);
  else            pwb[i - 196608] = f2bf(pw[i - 196608]);
}

// ---------------------------------------------------------------------------
// Kernel 1: CPB MLP -> tab[225][8] fp32
// ---------------------------------------------------------------------------
__global__ void k_cpb_mlp(const float* __restrict__ w1, const float* __restrict__ b1,
                          const float* __restrict__ w2, float* __restrict__ tab){
  const int e = blockIdx.x;        // 0..224
  const int c = threadIdx.x;       // 0..255
  const float a0 = (float)(e / LW - 7);
  const float a1 = (float)(e % LW - 7);
  const float cx = copysignf(log2f(fabsf(a0)*(8.f/7.f) + 1.f) * (1.f/3.f), a0);
  const float cy = copysignf(log2f(fabsf(a1)*(8.f/7.f) + 1.f) * (1.f/3.f), a1);
  float pre = (cx*w1[2*c] + cy*w1[2*c+1] + b1[c]) * BNS;
  float hid = pre / (1.f + __expf(-pre));   // silu
  __shared__ float hl[256];
  hl[c] = hid;
  __syncthreads();
  if (c < 8){
    float s = 0.f;
    for (int i = 0; i < 256; ++i) s += hl[i] * w2[c*256 + i];
    tab[e*8 + c] = s * BNS;
  }
}

// ---------------------------------------------------------------------------
// Kernel 2: biasQ[h][query q][key] = 16*sigmoid(tab[rpi(q,key)][h])
// (query-major so softmax loads are float4 along key)
// ---------------------------------------------------------------------------
__global__ void k_bias_expand(const float* __restrict__ tab, float* __restrict__ biasQ){
  const int id = blockIdx.x*256 + threadIdx.x;   // h*4096 + q*64 + key
  const int key = id & 63;
  const int q   = (id >> 6) & 63;
  const int h   = id >> 12;
  const int dy = (q >> 3) - (key >> 3) + 7;
  const int dx = (q & 7)  - (key & 7)  + 7;
  const float v = tab[(dy*LW + dx)*8 + h];
  biasQ[id] = 16.f / (1.f + __expf(-v));
}

// ---------------------------------------------------------------------------
// Kernel 3: fused qkv GEMM + attention, WAVE-PER-HEAD, ONE barrier.
// Block = window, 512 thr = 8 waves; wave h computes AND consumes head h's
// q,k,v (6 weight row-tiles). After xs staging there is NO cross-wave data
// sharing -> no further __syncthreads.
// All layout transposes (D-layout MFMA output -> A/B-operand layouts) bounce
// through a 4608B PER-WAVE private LDS region, reused sequentially:
//   q: [32 tok][40 d] x2 halves -> qf[4]   (B-layout frags)
//   k: same                      -> ka[4]  (A-layout frags)
//   P: per qt [16 q][72 key]     -> pa[qt][2]
//   v: [32 d][72 tok]            -> bv[2][2] + coalesced global V store
// Softmax 1/sum folded into P pack -> PV output is normalized; O stored as
// float4 tiles directly (no obuf/linv).
// LDS: xs 33792 + 8*4608 = 70656 -> 2 blocks/CU. launch_bounds caps VGPR 128.
// ---------------------------------------------------------------------------
__global__ __launch_bounds__(512, 4) void k_qkv_attn(
    const float* __restrict__ x, const u16* __restrict__ qwb,
    const float* __restrict__ qb, const float* __restrict__ biasQ,
    float* __restrict__ xout, u16* __restrict__ vout){
  const int win = blockIdx.x;
  const int b = win >> 6, wy = (win >> 3) & 7, wx = win & 7;
  __shared__ __align__(16) char smem[70656];
  u16* xs = (u16*)smem;                              // [64 tok][264 c]
  const int tid  = threadIdx.x;
  const int wave = tid >> 6, lane = tid & 63;
  const int quad = lane >> 4, l16 = lane & 15;
  u16* vbw = (u16*)(smem + 33792 + wave*4608);       // per-wave bounce

  // ---- stage x -> xs bf16 [tok][c] ----
  const float* xbase = x + (size_t)b*256*4096 + (size_t)(wy*8)*64 + wx*8;
  for (int i = tid; i < 4096; i += 512){
    const int c  = i >> 4;
    const int g  = i & 15;
    const int py = g >> 1, xh = (g & 1) * 4;
    float4 v4 = *(const float4*)&xbase[(size_t)c*4096 + py*64 + xh];
    const int n0 = py*8 + xh;
    xs[(n0+0)*264 + c] = f2bf(v4.x);
    xs[(n0+1)*264 + c] = f2bf(v4.y);
    xs[(n0+2)*264 + c] = f2bf(v4.z);
    xs[(n0+3)*264 + c] = f2bf(v4.w);
  }
  __syncthreads();   // the ONLY barrier

  const int h = wave;
  const f32x4 zero4 = {0.f, 0.f, 0.f, 0.f};

  // GEMM for one section (0=q,1=k,2=v): 2 row-tiles x 4 token-tiles, K=256.
  // 8 independent chains; af half-K staged; B-frags shared across row-tiles.
  // Output: bias-added bf16 pair-words w[rt][tt][u]:
  //   w[rt][tt][u] = bf16(D[d=rt*16+quad*4+2u][tok=tt*16+l16]) |
  //                  bf16(D[d=rt*16+quad*4+2u+1][...]) << 16
  auto run_gemm = [&](int sec, u32 (&w)[2][4][2]){
    f32x4 acc[2][4];
    #pragma unroll
    for (int rt = 0; rt < 2; ++rt)
      #pragma unroll
      for (int tt = 0; tt < 4; ++tt) acc[rt][tt] = zero4;
    #pragma unroll
    for (int kh2 = 0; kh2 < 2; ++kh2){
      bf16x8 af[2][4];
      #pragma unroll
      for (int rt = 0; rt < 2; ++rt){
        const int wr = sec*256 + h*32 + rt*16 + l16;
        #pragma unroll
        for (int kc = 0; kc < 4; ++kc)
          af[rt][kc] = *(const bf16x8*)(qwb + (size_t)wr*256 + (kh2*4 + kc)*32 + quad*8);
      }
      #pragma unroll
      for (int kc = 0; kc < 4; ++kc){
        #pragma unroll
        for (int tt = 0; tt < 4; ++tt){
          bf16x8 bf = *(const bf16x8*)&xs[(tt*16 + l16)*264 + (kh2*4 + kc)*32 + quad*8];
          acc[0][tt] = __builtin_amdgcn_mfma_f32_16x16x32_bf16(af[0][kc], bf, acc[0][tt], 0, 0, 0);
          acc[1][tt] = __builtin_amdgcn_mfma_f32_16x16x32_bf16(af[1][kc], bf, acc[1][tt], 0, 0, 0);
        }
      }
    }
    #pragma unroll
    for (int rt = 0; rt < 2; ++rt){
      float4 b4 = *(const float4*)&qb[sec*256 + h*32 + rt*16 + quad*4];
      #pragma unroll
      for (int tt = 0; tt < 4; ++tt){
        w[rt][tt][0] = (u32)f2bf(acc[rt][tt][0] + b4.x) |
                       ((u32)f2bf(acc[rt][tt][1] + b4.y) << 16);
        w[rt][tt][1] = (u32)f2bf(acc[rt][tt][2] + b4.z) |
                       ((u32)f2bf(acc[rt][tt][3] + b4.w) << 16);
      }
    }
  };

  // D-layout -> [tok][d] bounce (two 32-token halves), read back as frags:
  // frag[tt]: lane(l16,quad) = rows tok tt*16+l16, d = quad*8..+7.
  auto bounce_td = [&](const u32 (&w)[2][4][2], bf16x8 (&frag)[4]){
    #pragma unroll
    for (int half = 0; half < 2; ++half){
      #pragma unroll
      for (int t2 = 0; t2 < 2; ++t2){     // tt = half*2 + t2
        const int tt = half*2 + t2;
        #pragma unroll
        for (int rt = 0; rt < 2; ++rt)
          #pragma unroll
          for (int u = 0; u < 2; ++u)
            *(u32*)&vbw[(t2*16 + l16)*40 + rt*16 + quad*4 + 2*u] = w[rt][tt][u];
      }
      #pragma unroll
      for (int t2 = 0; t2 < 2; ++t2)
        frag[half*2 + t2] = *(const bf16x8*)&vbw[(t2*16 + l16)*40 + quad*8];
    }
  };

  // ---- q, k GEMMs -> register fragments ----
  bf16x8 qf[4], ka[4];
  {
    u32 wq[2][4][2];
    run_gemm(0, wq);
    bounce_td(wq, qf);
  }
  {
    u32 wk[2][4][2];
    run_gemm(1, wk);
    bounce_td(wk, ka);
  }

  // ---- QK^T + softmax + P (per query-tile), bounce to A-layout pa ----
  bf16x8 pa[4][2];
  #pragma unroll
  for (int qt = 0; qt < 4; ++qt){
    f32x4 st[4];
    #pragma unroll
    for (int kt = 0; kt < 4; ++kt)
      st[kt] = __builtin_amdgcn_mfma_f32_16x16x32_bf16(ka[kt], qf[qt], zero4, 0, 0, 0);
    float4 bq[4];
    #pragma unroll
    for (int kt = 0; kt < 4; ++kt)
      bq[kt] = *(const float4*)&biasQ[(h<<12) + (qt*16 + l16)*64 + kt*16 + quad*4];
    // lane holds S[key=kt*16+quad*4+r][q=qt*16+l16]
    float sc[16], mx = -1e30f;
    #pragma unroll
    for (int kt = 0; kt < 4; ++kt)
      #pragma unroll
      for (int r = 0; r < 4; ++r){
        const float v = st[kt][r]*SCALE + ((const float*)&bq[kt])[r];
        sc[kt*4+r] = v; mx = fmaxf(mx, v);
      }
    mx = fmaxf(mx, __shfl_xor(mx, 16));
    mx = fmaxf(mx, __shfl_xor(mx, 32));
    float sum = 0.f;
    #pragma unroll
    for (int i = 0; i < 16; ++i){ sc[i] = __expf(sc[i] - mx); sum += sc[i]; }
    sum += __shfl_xor(sum, 16);
    sum += __shfl_xor(sum, 32);
    const float inv = 1.f / sum;
    // pack normalized P pairs, bounce [16 q][72 key], read A-layout frags
    #pragma unroll
    for (int kt = 0; kt < 4; ++kt){
      u32 w0 = (u32)f2bf(sc[kt*4+0]*inv) | ((u32)f2bf(sc[kt*4+1]*inv) << 16);
      u32 w1 = (u32)f2bf(sc[kt*4+2]*inv) | ((u32)f2bf(sc[kt*4+3]*inv) << 16);
      *(u32*)&vbw[l16*72 + kt*16 + quad*4 + 0] = w0;
      *(u32*)&vbw[l16*72 + kt*16 + quad*4 + 2] = w1;
    }
    pa[qt][0] = *(const bf16x8*)&vbw[l16*72 +  0 + quad*8];
    pa[qt][1] = *(const bf16x8*)&vbw[l16*72 + 32 + quad*8];
  }

  // ---- v GEMM -> transposed bounce [32 d][72 tok] ----
  {
    u32 wv[2][4][2];
    run_gemm(2, wv);
    #pragma unroll
    for (int rt = 0; rt < 2; ++rt)
      #pragma unroll
      for (int tt = 0; tt < 4; ++tt)
        #pragma unroll
        for (int u = 0; u < 2; ++u){
          vbw[(rt*16 + quad*4 + 2*u + 0)*72 + tt*16 + l16] = (u16)(wv[rt][tt][u] & 0xFFFFu);
          vbw[(rt*16 + quad*4 + 2*u + 1)*72 + tt*16 + l16] = (u16)(wv[rt][tt][u] >> 16);
        }
  }
  bf16x8 bv[2][2];
  #pragma unroll
  for (int dt = 0; dt < 2; ++dt)
    #pragma unroll
    for (int kh = 0; kh < 2; ++kh)
      bv[dt][kh] = *(const bf16x8*)&vbw[(dt*16 + l16)*72 + kh*32 + quad*8];

  // ---- V global store (bf16 image layout), coalesced u16x8 ----
  {
    const int d  = lane >> 1;
    #pragma unroll
    for (int i = 0; i < 4; ++i){
      const int ch = (lane & 1)*4 + i;
      u16x8 v8 = *(const u16x8*)&vbw[d*72 + ch*8];
      *(u16x8*)&vout[((size_t)(b*256 + h*32 + d))*4096 + (size_t)(wy*8 + ch)*64 + wx*8] = v8;
    }
  }

  // ---- PV + direct normalized O store ----
  #pragma unroll
  for (int qt = 0; qt < 4; ++qt){
    #pragma unroll
    for (int dt = 0; dt < 2; ++dt){
      f32x4 o = __builtin_amdgcn_mfma_f32_16x16x32_bf16(pa[qt][0], bv[dt][0], zero4, 0, 0, 0);
      o = __builtin_amdgcn_mfma_f32_16x16x32_bf16(pa[qt][1], bv[dt][1], o, 0, 0, 0);
      float4 o4; o4.x = o[0]; o4.y = o[1]; o4.z = o[2]; o4.w = o[3];
      *(float4*)&xout[((size_t)(b*256 + h*32 + dt*16 + l16))*4096
                      + (size_t)(wy*8 + qt*2 + (quad>>1))*64 + wx*8 + (quad&1)*4] = o4;
    }
  }
}

// ---------------------------------------------------------------------------
// Kernel 4: depthwise 7x7 + residual, IN PLACE on io (fp32).
// Register-blocked 4x4 outputs; staging vectorized (u16x8 loads).
// ---------------------------------------------------------------------------
__global__ __launch_bounds__(256) void k_dwconv(
    const u16* __restrict__ vimg, const float* __restrict__ dww,
    float* __restrict__ io){
  const int b = blockIdx.x >> 8, c = blockIdx.x & 255;
  __shared__ float tile[70*72];   // zero-padded halo
  const size_t base = ((size_t)(b*256 + c)) * 4096;
  for (int i = threadIdx.x; i < 1260; i += 256)
    *(float4*)&tile[i*4] = (float4){0.f, 0.f, 0.f, 0.f};
  float w[49];
  #pragma unroll
  for (int j = 0; j < 49; ++j) w[j] = dww[c*49 + j];
  __syncthreads();
  for (int i = threadIdx.x; i < 512; i += 256){
    const int y = i >> 3, x8 = (i & 7) * 8;
    u16x8 v = *(const u16x8*)&vimg[base + y*64 + x8];
    #pragma unroll
    for (int j = 0; j < 8; ++j) tile[(y+3)*72 + x8 + 3 + j] = bf2f(v[j]);
  }
  __syncthreads();

  const int x0 = (threadIdx.x & 15) * 4;
  const int y0 = (threadIdx.x >> 4) * 4;
  float acc[4][4];
  #pragma unroll
  for (int i = 0; i < 4; ++i)
    #pragma unroll
    for (int j = 0; j < 4; ++j) acc[i][j] = 0.f;

  #pragma unroll
  for (int ty = 0; ty < 10; ++ty){
    const float* rp = &tile[(y0 + ty)*72 + x0];
    float r[12];
    *(float4*)&r[0] = *(const float4*)&rp[0];
    *(float4*)&r[4] = *(const float4*)&rp[4];
    *(float4*)&r[8] = *(const float4*)&rp[8];
    #pragma unroll
    for (int oy = 0; oy < 4; ++oy){
      if (ty >= oy && ty - oy <= 6){
        const int ky = ty - oy;
        #pragma unroll
        for (int ox = 0; ox < 4; ++ox)
          #pragma unroll
          for (int kx = 0; kx < 7; ++kx)
            acc[oy][ox] += w[ky*7 + kx] * r[ox + kx];
      }
    }
  }
  #pragma unroll
  for (int oy = 0; oy < 4; ++oy){
    const size_t gi = base + (size_t)(y0 + oy)*64 + x0;
    float4 res = *(const float4*)&io[gi];
    res.x += acc[oy][0]; res.y += acc[oy][1];
    res.z += acc[oy][2]; res.w += acc[oy][3];
    *(float4*)&io[gi] = res;
  }
}

// ---------------------------------------------------------------------------
// Kernel 5: proj GEMM per image row (MFMA), IN PLACE on io fp32.
// o-tile pairs with af in regs, kc-outer, 8 independent chains; float4 staging.
// ---------------------------------------------------------------------------
__global__ __launch_bounds__(256) void k_proj(
    const u16* __restrict__ pwb, const float* __restrict__ pb,
    float* __restrict__ io){
  const int row = blockIdx.x;           // b*64 + y
  const int b = row >> 6, y = row & 63;
  __shared__ __align__(16) u16 ts[64*264];   // [pixel n][c] bf16, pad +8
  const float* tbase = io + (size_t)b*256*4096 + (size_t)y*64;
  for (int i = threadIdx.x; i < 4096; i += 256){
    const int c = i >> 4, n0 = (i & 15) * 4;
    float4 v4 = *(const float4*)&tbase[(size_t)c*4096 + n0];
    ts[(n0+0)*264 + c] = f2bf(v4.x);
    ts[(n0+1)*264 + c] = f2bf(v4.y);
    ts[(n0+2)*264 + c] = f2bf(v4.z);
    ts[(n0+3)*264 + c] = f2bf(v4.w);
  }
  __syncthreads();
  const int wave = threadIdx.x >> 6, lane = threadIdx.x & 63;
  const int quad = lane >> 4, l16 = lane & 15;
  const f32x4 zero4 = {0.f, 0.f, 0.f, 0.f};
  #pragma unroll
  for (int op = 0; op < 2; ++op){        // o-tile pairs
    bf16x8 af2[2][8];
    #pragma unroll
    for (int oj = 0; oj < 2; ++oj){
      const int orow = (wave*4 + op*2 + oj)*16 + l16;
      #pragma unroll
      for (int kc = 0; kc < 8; ++kc)
        af2[oj][kc] = *(const bf16x8*)(pwb + (size_t)orow*256 + kc*32 + quad*8);
    }
    f32x4 acc[2][4];
    #pragma unroll
    for (int oj = 0; oj < 2; ++oj)
      #pragma unroll
      for (int nt = 0; nt < 4; ++nt) acc[oj][nt] = zero4;
    #pragma unroll
    for (int kc = 0; kc < 8; ++kc){
      bf16x8 bf[4];
      #pragma unroll
      for (int nt = 0; nt < 4; ++nt)
        bf[nt] = *(const bf16x8*)&ts[(nt*16 + l16)*264 + kc*32 + quad*8];
      #pragma unroll
      for (int oj = 0; oj < 2; ++oj)
        #pragma unroll
        for (int nt = 0; nt < 4; ++nt)
          acc[oj][nt] = __builtin_amdgcn_mfma_f32_16x16x32_bf16(af2[oj][kc], bf[nt], acc[oj][nt], 0, 0, 0);
    }
    #pragma unroll
    for (int oj = 0; oj < 2; ++oj){
      const int ot = wave*4 + op*2 + oj;
      #pragma unroll
      for (int nt = 0; nt < 4; ++nt)
        #pragma unroll
        for (int r = 0; r < 4; ++r){
          const int o = ot*16 + quad*4 + r;
          io[((size_t)(b*256 + o))*4096 + (size_t)y*64 + nt*16 + l16] = acc[oj][nt][r] + pb[o];
        }
    }
  }
}

// ---------------------------------------------------------------------------
extern "C" void kernel_launch(void* const* d_in, const int* in_sizes, int n_in,
                              void* d_out, int out_size, void* d_ws, size_t ws_size,
                              hipStream_t stream){
  const float* x   = (const float*)d_in[0];
  const float* qw  = (const float*)d_in[1];
  const float* qb  = (const float*)d_in[2];
  const float* pw  = (const float*)d_in[3];
  const float* pb  = (const float*)d_in[4];
  const float* w1  = (const float*)d_in[5];
  const float* b1  = (const float*)d_in[6];
  const float* w2  = (const float*)d_in[7];
  const float* dww = (const float*)d_in[8];

  // ws: tab 8KB | biasQ 128KB | qwb 384KB | pwb 128KB | vimg 32MB (~34.2 MB)
  char* ws = (char*)d_ws;
  float* tab   = (float*)(ws);
  float* biasQ = (float*)(ws + 8192);
  u16*   qwb   = (u16*)  (ws + 139264);
  u16*   pwb   = (u16*)  (ws + 532480);
  u16*   vimg  = (u16*)  (ws + 663552);
  float* out   = (float*)d_out;          // doubles as attn-out intermediate

  k_cvt_w      <<<1024, 256, 0, stream>>>(qw, pw, qwb, pwb);
  k_cpb_mlp    <<<225,  256, 0, stream>>>(w1, b1, w2, tab);
  k_bias_expand<<<128,  256, 0, stream>>>(tab, biasQ);
  k_qkv_attn   <<<1024, 512, 0, stream>>>(x, qwb, qb, biasQ, out, vimg);
  k_dwconv     <<<4096, 256, 0, stream>>>(vimg, dww, out);
  k_proj       <<<1024, 256, 0, stream>>>(pwb, pb, out);
}